// Round 18
// baseline (110.524 us; speedup 1.0000x reference)
//
#include <hip/hip_runtime.h>
#include <hip/hip_bf16.h>

#define DIN 128
#define HC  128
#define NH  4

#define CHUNK_LOG 14                 // 16384 edges per chunk
#define CNK       (1 << CHUNK_LOG)
#define HIST_BYTES 100352            // ceil(50000/2)*4 packed-ushort counters

#define GB 256                       // GEMM blocks in fused kernel
#define SB 768                       // scatter blocks (GB+SB = 4 blocks/CU)

typedef __attribute__((ext_vector_type(8))) short short8;
typedef __attribute__((ext_vector_type(4))) float floatx4;

__device__ inline short f2bf_bits(float f) {
    __hip_bfloat16 t = __float2bfloat16(f);
    return *reinterpret_cast<short*>(&t);
}
__device__ inline float bfbits2f(unsigned short u) {
    union { unsigned int i; float f; } c; c.i = ((unsigned int)u) << 16; return c.f;
}

// ---------------------------------------------------------------------------
// Full-range LDS histogram, one block per 16K-edge chunk, 1024 threads,
// 4-deep ILP. 52 blocks -> 52 CUs, 4 dependent atomic rounds per block.
// Also zeroes the scan1 handshake flag (runs strictly before scan1).
// ---------------------------------------------------------------------------
__global__ __launch_bounds__(1024) void hist(
    const int* __restrict__ src, unsigned short* __restrict__ cnt,
    unsigned short* __restrict__ rank16, int* __restrict__ flag,
    int n, int E, int total)
{
    __shared__ unsigned int histo[HIST_BYTES / 4];
    if (blockIdx.x == 0 && threadIdx.x == 0) *flag = 0;
    const int c = blockIdx.x;
    const int nInts = (n + 1) >> 1;
    for (int u = threadIdx.x; u < nInts; u += 1024) histo[u] = 0u;
    __syncthreads();

    const int e0 = c << CHUNK_LOG;
    const int e1 = min(e0 + CNK, total);
    for (int base = e0; base < e1; base += 4096) {
        int ii[4], ee[4];
        #pragma unroll
        for (int q = 0; q < 4; ++q) {
            const int e = base + q * 1024 + (int)threadIdx.x;
            ee[q] = e;
            ii[q] = (e < e1) ? ((e < E) ? src[e] : (e - E)) : -1;
        }
        #pragma unroll
        for (int q = 0; q < 4; ++q) {
            if (ii[q] >= 0) {
                const unsigned int sh  = (unsigned)(ii[q] & 1) * 16u;
                const unsigned int old = atomicAdd(&histo[ii[q] >> 1], 1u << sh);
                rank16[ee[q]] = (unsigned short)((old >> sh) & 0xffffu);
            }
        }
    }
    __syncthreads();
    unsigned short* row = cnt + (size_t)c * n;
    for (int u = threadIdx.x; u < n; u += 1024)
        row[u] = (unsigned short)((histo[u >> 1] >> ((u & 1) * 16)) & 0xffffu);
}

// ---------------------------------------------------------------------------
// scan1 (+ merged scan2 finale): per node i, serial exclusive scan of
// cnt[c][i] over chunks -> deg; intra-block exclusive scan -> rowptr + bsum.
// The LAST block to finish (device-scope atomic flag) scans bsum -> boff
// (nb=196 <= 256 threads), saving the separate scan2 launch.
// ---------------------------------------------------------------------------
__global__ __launch_bounds__(256) void scan1(
    unsigned short* __restrict__ cnt, int* __restrict__ rowptr,
    int* __restrict__ bsum, int* __restrict__ boff, int* __restrict__ flag,
    int n, int nchunks, int nb)
{
    __shared__ int sh[256];
    __shared__ int lastFlag;
    const int t = threadIdx.x;
    const int i = blockIdx.x * 256 + t;
    int run = 0;
    if (i < n) {
        for (int c = 0; c < nchunks; ++c) {
            const size_t idx = (size_t)c * n + i;
            const int v = cnt[idx];
            cnt[idx] = (unsigned short)run;
            run += v;
        }
    }
    sh[t] = run;
    __syncthreads();
    #pragma unroll
    for (int off = 1; off < 256; off <<= 1) {
        const int u = (t >= off) ? sh[t - off] : 0;
        __syncthreads();
        sh[t] += u;
        __syncthreads();
    }
    if (i < n) rowptr[i] = sh[t] - run;      // exclusive within block
    if (t == 255) bsum[blockIdx.x] = sh[255];
    __syncthreads();                         // own bsum written
    __threadfence();                         // release: bsum device-visible
    if (t == 0) lastFlag = (atomicAdd(flag, 1) == nb - 1);
    __syncthreads();
    if (lastFlag) {
        __threadfence();                     // acquire side
        const int v = (t < nb) ? bsum[t] : 0;
        sh[t] = v;
        __syncthreads();
        #pragma unroll
        for (int off = 1; off < 256; off <<= 1) {
            const int u = (t >= off) ? sh[t - off] : 0;
            __syncthreads();
            sh[t] += u;
            __syncthreads();
        }
        if (t < nb) boff[t] = sh[t] - v;
    }
}

// ---------------------------------------------------------------------------
// FUSED kernel, block-range split (35KB LDS -> 4 blocks/CU):
//   blocks [0, GB)       : h = bf16(x @ W + b) via MFMA + fused ali/alj logits
//   blocks [GB, GB+SB)   : atomic-free CSR scatter (random ushort writes ride
//                          under the GEMM's MFMA/LDS work)
// ---------------------------------------------------------------------------
__global__ __launch_bounds__(256) void gemm_scatter(
    const float* __restrict__ x, const float* __restrict__ W,
    const float* __restrict__ b, const float* __restrict__ att,
    __hip_bfloat16* __restrict__ h, float* __restrict__ ali,
    float* __restrict__ alj,
    const int* __restrict__ src, const int* __restrict__ dst,
    const unsigned short* __restrict__ rank16,
    const unsigned short* __restrict__ cnt,
    const int* __restrict__ rowptr, const int* __restrict__ boff,
    unsigned short* __restrict__ csr,
    int n, int ntiles, int E, int total)
{
    __shared__ __hip_bfloat16 Wt[DIN][136];

    if (blockIdx.x >= GB) {
        // ---------------- scatter part ----------------
        for (int e = (blockIdx.x - GB) * 256 + threadIdx.x; e < total;
             e += SB * 256) {
            int i, j;
            if (e < E) { i = src[e]; j = dst[e]; }
            else       { i = e - E;  j = i; }
            const int pos = rowptr[i] + boff[i >> 8]
                          + (int)cnt[(size_t)(e >> CHUNK_LOG) * n + i]
                          + (int)rank16[e];
            csr[pos] = (unsigned short)j;
        }
        return;
    }

    // ---------------- GEMM part ----------------
    for (int idx = threadIdx.x; idx < DIN * HC; idx += 256) {
        const int k = idx >> 7, c = idx & 127;
        Wt[c][k] = __float2bfloat16(W[idx]);
    }
    __syncthreads();

    const int lane = threadIdx.x & 63;
    const int l15 = lane & 15, lg = lane >> 4;

    short8 bf[8][4];
    #pragma unroll
    for (int ct = 0; ct < 8; ++ct)
        #pragma unroll
        for (int ks = 0; ks < 4; ++ks)
            bf[ct][ks] = *(const short8*)(&Wt[ct * 16 + l15][ks * 32 + lg * 8]);

    float bc[8], ai_l[8], aj_l[8];
    #pragma unroll
    for (int ct = 0; ct < 8; ++ct) {
        bc[ct]   = b[ct * 16 + l15];
        ai_l[ct] = att[(ct >> 1) * 64 + (ct & 1) * 16 + l15];
        aj_l[ct] = att[(ct >> 1) * 64 + 32 + (ct & 1) * 16 + l15];
    }

    const int gw = (blockIdx.x * 256 + threadIdx.x) >> 6;
    const int nw = (GB * 256) >> 6;
    for (int tile = gw; tile < ntiles; tile += nw) {
        int row = tile * 16 + l15;
        if (row >= n) row = n - 1;              // safe duplicate load
        floatx4 acc[8];
        #pragma unroll
        for (int ct = 0; ct < 8; ++ct) acc[ct] = (floatx4)0.f;

        #pragma unroll
        for (int ks = 0; ks < 4; ++ks) {
            const float4 f0 = *(const float4*)(x + (size_t)row * DIN + ks * 32 + lg * 8);
            const float4 f1 = *(const float4*)(x + (size_t)row * DIN + ks * 32 + lg * 8 + 4);
            short8 af;
            af[0] = f2bf_bits(f0.x); af[1] = f2bf_bits(f0.y);
            af[2] = f2bf_bits(f0.z); af[3] = f2bf_bits(f0.w);
            af[4] = f2bf_bits(f1.x); af[5] = f2bf_bits(f1.y);
            af[6] = f2bf_bits(f1.z); af[7] = f2bf_bits(f1.w);
            #pragma unroll
            for (int ct = 0; ct < 8; ++ct)
                acc[ct] = __builtin_amdgcn_mfma_f32_16x16x32_bf16(
                    af, bf[ct][ks], acc[ct], 0, 0, 0);
        }

        #pragma unroll
        for (int reg = 0; reg < 4; ++reg) {
            const int r = tile * 16 + lg * 4 + reg;

            // h write (bf16)
            #pragma unroll
            for (int ct = 0; ct < 8; ++ct)
                if (r < n)
                    h[(size_t)r * HC + ct * 16 + l15] =
                        __float2bfloat16(acc[ct][reg] + bc[ct]);

            // fused logits: per-head dot over this row's 128 cols
            float pi[4], pj[4];
            #pragma unroll
            for (int hd = 0; hd < 4; ++hd) {
                float vi = 0.f, vj = 0.f;
                #pragma unroll
                for (int q = 0; q < 2; ++q) {
                    const int ct = hd * 2 + q;
                    const float hv = acc[ct][reg] + bc[ct];
                    vi = fmaf(hv, ai_l[ct], vi);
                    vj = fmaf(hv, aj_l[ct], vj);
                }
                #pragma unroll
                for (int m = 1; m <= 8; m <<= 1) {
                    vi += __shfl_xor(vi, m);
                    vj += __shfl_xor(vj, m);
                }
                pi[hd] = vi; pj[hd] = vj;
            }
            if (l15 < 8 && r < n) {
                const int hd = l15 & 3;
                float wi = pi[0];
                wi = (hd == 1) ? pi[1] : wi;
                wi = (hd == 2) ? pi[2] : wi;
                wi = (hd == 3) ? pi[3] : wi;
                float wj = pj[0];
                wj = (hd == 1) ? pj[1] : wj;
                wj = (hd == 2) ? pj[2] : wj;
                wj = (hd == 3) ? pj[3] : wj;
                if (l15 < 4) ali[(size_t)r * 4 + hd] = wi;
                else         alj[(size_t)r * 4 + hd] = wj;
            }
        }
    }
}

// ---------------------------------------------------------------------------
// ONE node per wave, edge list SPLIT between the two half-waves (even edges
// -> half 0, odd -> half 1). Each half covers all 128 cols (32 lanes x
// ushort4), unroll-4 per half = 8 edges in flight per wave. One
// shfl_xor(32) folds the halves; half 0 stores float4 with bias+ReLU.
// ---------------------------------------------------------------------------
__global__ __launch_bounds__(256) void aggregate_csr(
    const int* __restrict__ rowptr, const int* __restrict__ boff,
    const unsigned short* __restrict__ csr,
    const float* __restrict__ ali, const float* __restrict__ alj,
    const __hip_bfloat16* __restrict__ h, const float* __restrict__ bias,
    float* __restrict__ out, int n, int total)
{
    const int lane = threadIdx.x & 63;
    const int l32  = lane & 31;
    const int half = lane >> 5;
    const int hh   = l32 >> 3;                  // head of cols [l32*4, l32*4+4)
    const int gw = (blockIdx.x * 256 + threadIdx.x) >> 6;
    const int nw = (gridDim.x * 256) >> 6;
    const unsigned short* hu = (const unsigned short*)h;
    const float b0 = bias[l32 * 4 + 0], b1 = bias[l32 * 4 + 1];
    const float b2 = bias[l32 * 4 + 2], b3 = bias[l32 * 4 + 3];

    for (int i = gw; i < n; i += nw) {
        const int rs = rowptr[i] + boff[i >> 8];
        const int re = (i + 1 == n) ? total
                                    : rowptr[i + 1] + boff[(i + 1) >> 8];
        const float aii = ali[(size_t)i * 4 + hh];

        float a0 = 0.f, a1 = 0.f, a2 = 0.f, a3 = 0.f, s = 0.f;
        int t = rs + half;                      // this half's stream: stride 2
        for (; t + 6 < re; t += 8) {            // 4 edges per half per iter
            int jj[4]; float ll[4]; ushort4 uu[4];
            #pragma unroll
            for (int q = 0; q < 4; ++q) jj[q] = csr[t + q * 2];
            #pragma unroll
            for (int q = 0; q < 4; ++q) ll[q] = alj[(size_t)jj[q] * 4 + hh];
            #pragma unroll
            for (int q = 0; q < 4; ++q)
                uu[q] = *(const ushort4*)(hu + (size_t)jj[q] * HC + l32 * 4);
            #pragma unroll
            for (int q = 0; q < 4; ++q) {
                float l = aii + ll[q];
                l = l > 0.f ? l : 0.2f * l;
                const float ex = __expf(l);
                s += ex;
                a0 = fmaf(ex, bfbits2f(uu[q].x), a0);
                a1 = fmaf(ex, bfbits2f(uu[q].y), a1);
                a2 = fmaf(ex, bfbits2f(uu[q].z), a2);
                a3 = fmaf(ex, bfbits2f(uu[q].w), a3);
            }
        }
        for (; t < re; t += 2) {
            const int j = csr[t];
            float l = aii + alj[(size_t)j * 4 + hh];
            l = l > 0.f ? l : 0.2f * l;
            const float ex = __expf(l);
            s += ex;
            const ushort4 u = *(const ushort4*)(hu + (size_t)j * HC + l32 * 4);
            a0 = fmaf(ex, bfbits2f(u.x), a0);
            a1 = fmaf(ex, bfbits2f(u.y), a1);
            a2 = fmaf(ex, bfbits2f(u.z), a2);
            a3 = fmaf(ex, bfbits2f(u.w), a3);
        }

        // fold the two halves (lane l and l+32 hold the same columns)
        a0 += __shfl_xor(a0, 32);
        a1 += __shfl_xor(a1, 32);
        a2 += __shfl_xor(a2, 32);
        a3 += __shfl_xor(a3, 32);
        s  += __shfl_xor(s, 32);

        if (half == 0) {
            const float inv = 1.0f / s;
            float o0 = fmaf(a0, inv, b0);
            float o1 = fmaf(a1, inv, b1);
            float o2 = fmaf(a2, inv, b2);
            float o3 = fmaf(a3, inv, b3);
            float4 ov;
            ov.x = o0 > 0.f ? o0 : 0.f;
            ov.y = o1 > 0.f ? o1 : 0.f;
            ov.z = o2 > 0.f ? o2 : 0.f;
            ov.w = o3 > 0.f ? o3 : 0.f;
            *(float4*)(out + (size_t)i * HC + l32 * 4) = ov;
        }
    }
}

extern "C" void kernel_launch(void* const* d_in, const int* in_sizes, int n_in,
                              void* d_out, int out_size, void* d_ws, size_t ws_size,
                              hipStream_t stream)
{
    const float* x    = (const float*)d_in[0];
    const int*   ei   = (const int*)d_in[1];     // int32 (harness convention)
    const float* W    = (const float*)d_in[2];
    const float* b    = (const float*)d_in[3];
    const float* att  = (const float*)d_in[4];
    const float* bias = (const float*)d_in[5];

    const int n     = in_sizes[0] / DIN;   // 50000
    const int E     = in_sizes[1] / 2;     // 800000
    const int total = E + n;

    const int* src = ei;        // e_i (segment index)
    const int* dst = ei + E;    // e_j (gather index)

    const int nchunks = (total + CNK - 1) >> CHUNK_LOG;   // 52
    const int nb      = (n + 255) / 256;                  // scan blocks (196)

    // workspace layout (~23 MB), 256B-aligned slices
    char* ws = (char*)d_ws;
    size_t off = 0;
    auto take = [&](size_t bytes) {
        char* p = ws + off;
        off += (bytes + 255) & ~(size_t)255;
        return p;
    };
    __hip_bfloat16* h   = (__hip_bfloat16*)take((size_t)n * HC * 2);
    float* ali    = (float*)take((size_t)n * NH * 4);
    float* alj    = (float*)take((size_t)n * NH * 4);
    int*   rowptr = (int*)take((size_t)(n + 1) * 4);
    int*   bsum   = (int*)take((size_t)nb * 4);
    int*   boff   = (int*)take((size_t)nb * 4);
    int*   flag   = (int*)take(256);
    unsigned short* cnt    = (unsigned short*)take((size_t)nchunks * n * 2);
    unsigned short* rank16 = (unsigned short*)take((size_t)total * 2);
    unsigned short* csr    = (unsigned short*)take((size_t)total * 2);

    float* out = (float*)d_out;

    hist<<<nchunks, 1024, 0, stream>>>(src, cnt, rank16, flag, n, E, total);
    scan1<<<nb, 256, 0, stream>>>(cnt, rowptr, bsum, boff, flag, n, nchunks, nb);

    const int ntiles = (n + 15) / 16;
    gemm_scatter<<<GB + SB, 256, 0, stream>>>(
        x, W, b, att, h, ali, alj,
        src, dst, rank16, cnt, rowptr, boff, csr,
        n, ntiles, E, total);

    const int nodeBlocks = (n + 3) / 4;            // 4 waves/block, 1 node/wave
    aggregate_csr<<<nodeBlocks, 256, 0, stream>>>(rowptr, boff, csr, ali, alj,
                                                  h, bias, out, n, total);
}

// Round 19
// 94.106 us; speedup vs baseline: 1.1745x; 1.1745x over previous
//
#include <hip/hip_runtime.h>
#include <hip/hip_bf16.h>

#define DIN 128
#define HC  128
#define NH  4

#define CHUNK_LOG 15                 // 32768 edges per chunk
#define CNK       (1 << CHUNK_LOG)
#define HIST_BYTES 100352            // ceil(50000/2)*4 packed-ushort counters

#define GB 256                       // GEMM blocks in fused kernel
#define SB 512                       // scatter blocks in fused kernel

typedef __attribute__((ext_vector_type(8))) short short8;
typedef __attribute__((ext_vector_type(4))) float floatx4;

__device__ inline short f2bf_bits(float f) {
    __hip_bfloat16 t = __float2bfloat16(f);
    return *reinterpret_cast<short*>(&t);
}
__device__ inline float bfbits2f(unsigned short u) {
    union { unsigned int i; float f; } c; c.i = ((unsigned int)u) << 16; return c.f;
}

// ---------------------------------------------------------------------------
// Full-range LDS histogram, one block per 32K-edge chunk, 1024 threads,
// 4-deep ILP (R13/R17 known-good configuration).
// ---------------------------------------------------------------------------
__global__ __launch_bounds__(1024) void hist(
    const int* __restrict__ src, unsigned short* __restrict__ cnt,
    unsigned short* __restrict__ rank16, int n, int E, int total)
{
    __shared__ unsigned int histo[HIST_BYTES / 4];
    const int c = blockIdx.x;
    const int nInts = (n + 1) >> 1;
    for (int u = threadIdx.x; u < nInts; u += 1024) histo[u] = 0u;
    __syncthreads();

    const int e0 = c << CHUNK_LOG;
    const int e1 = min(e0 + CNK, total);
    for (int base = e0; base < e1; base += 4096) {
        int ii[4], ee[4];
        #pragma unroll
        for (int q = 0; q < 4; ++q) {
            const int e = base + q * 1024 + (int)threadIdx.x;
            ee[q] = e;
            ii[q] = (e < e1) ? ((e < E) ? src[e] : (e - E)) : -1;
        }
        #pragma unroll
        for (int q = 0; q < 4; ++q) {
            if (ii[q] >= 0) {
                const unsigned int sh  = (unsigned)(ii[q] & 1) * 16u;
                const unsigned int old = atomicAdd(&histo[ii[q] >> 1], 1u << sh);
                rank16[ee[q]] = (unsigned short)((old >> sh) & 0xffffu);
            }
        }
    }
    __syncthreads();
    unsigned short* row = cnt + (size_t)c * n;
    for (int u = threadIdx.x; u < n; u += 1024)
        row[u] = (unsigned short)((histo[u >> 1] >> ((u & 1) * 16)) & 0xffffu);
}

// ---------------------------------------------------------------------------
// scan1: per node i, serial exclusive scan of cnt[c][i] over chunks
// (chunk-prefix written back into cnt) -> deg; intra-block exclusive scan
// of deg -> rowptr + per-block sums. All cnt accesses coalesced.
// ---------------------------------------------------------------------------
__global__ __launch_bounds__(256) void scan1(
    unsigned short* __restrict__ cnt, int* __restrict__ rowptr,
    int* __restrict__ bsum, int n, int nchunks)
{
    __shared__ int sh[256];
    const int t = threadIdx.x;
    const int i = blockIdx.x * 256 + t;
    int run = 0;
    if (i < n) {
        for (int c = 0; c < nchunks; ++c) {
            const size_t idx = (size_t)c * n + i;
            const int v = cnt[idx];
            cnt[idx] = (unsigned short)run;
            run += v;
        }
    }
    sh[t] = run;
    __syncthreads();
    #pragma unroll
    for (int off = 1; off < 256; off <<= 1) {
        const int u = (t >= off) ? sh[t - off] : 0;
        __syncthreads();
        sh[t] += u;
        __syncthreads();
    }
    if (i < n) rowptr[i] = sh[t] - run;      // exclusive within block
    if (t == 255) bsum[blockIdx.x] = sh[255];
}

// single block: exclusive scan of block sums -> boff
__global__ __launch_bounds__(1024) void scan2(
    const int* __restrict__ bsum, int* __restrict__ boff, int nb)
{
    __shared__ int sh[1024];
    const int t = threadIdx.x;
    const int v = (t < nb) ? bsum[t] : 0;
    sh[t] = v;
    __syncthreads();
    #pragma unroll
    for (int off = 1; off < 1024; off <<= 1) {
        const int u = (t >= off) ? sh[t - off] : 0;
        __syncthreads();
        sh[t] += u;
        __syncthreads();
    }
    if (t < nb) boff[t] = sh[t] - v;
}

// ---------------------------------------------------------------------------
// FUSED kernel, block-range split (35KB LDS -> 4 blocks/CU):
//   blocks [0, GB)       : h = bf16(x @ W + b) via MFMA + fused ali/alj logits
//   blocks [GB, GB+SB)   : atomic-free CSR scatter (random ushort writes ride
//                          under the GEMM's MFMA/LDS work)
// ---------------------------------------------------------------------------
__global__ __launch_bounds__(256) void gemm_scatter(
    const float* __restrict__ x, const float* __restrict__ W,
    const float* __restrict__ b, const float* __restrict__ att,
    __hip_bfloat16* __restrict__ h, float* __restrict__ ali,
    float* __restrict__ alj,
    const int* __restrict__ src, const int* __restrict__ dst,
    const unsigned short* __restrict__ rank16,
    const unsigned short* __restrict__ cnt,
    const int* __restrict__ rowptr, const int* __restrict__ boff,
    unsigned short* __restrict__ csr,
    int n, int ntiles, int E, int total)
{
    __shared__ __hip_bfloat16 Wt[DIN][136];

    if (blockIdx.x >= GB) {
        // ---------------- scatter part ----------------
        for (int e = (blockIdx.x - GB) * 256 + threadIdx.x; e < total;
             e += SB * 256) {
            int i, j;
            if (e < E) { i = src[e]; j = dst[e]; }
            else       { i = e - E;  j = i; }
            const int pos = rowptr[i] + boff[i >> 8]
                          + (int)cnt[(size_t)(e >> CHUNK_LOG) * n + i]
                          + (int)rank16[e];
            csr[pos] = (unsigned short)j;
        }
        return;
    }

    // ---------------- GEMM part ----------------
    for (int idx = threadIdx.x; idx < DIN * HC; idx += 256) {
        const int k = idx >> 7, c = idx & 127;
        Wt[c][k] = __float2bfloat16(W[idx]);
    }
    __syncthreads();

    const int lane = threadIdx.x & 63;
    const int l15 = lane & 15, lg = lane >> 4;

    short8 bf[8][4];
    #pragma unroll
    for (int ct = 0; ct < 8; ++ct)
        #pragma unroll
        for (int ks = 0; ks < 4; ++ks)
            bf[ct][ks] = *(const short8*)(&Wt[ct * 16 + l15][ks * 32 + lg * 8]);

    float bc[8], ai_l[8], aj_l[8];
    #pragma unroll
    for (int ct = 0; ct < 8; ++ct) {
        bc[ct]   = b[ct * 16 + l15];
        ai_l[ct] = att[(ct >> 1) * 64 + (ct & 1) * 16 + l15];
        aj_l[ct] = att[(ct >> 1) * 64 + 32 + (ct & 1) * 16 + l15];
    }

    const int gw = (blockIdx.x * 256 + threadIdx.x) >> 6;
    const int nw = (GB * 256) >> 6;
    for (int tile = gw; tile < ntiles; tile += nw) {
        int row = tile * 16 + l15;
        if (row >= n) row = n - 1;              // safe duplicate load
        floatx4 acc[8];
        #pragma unroll
        for (int ct = 0; ct < 8; ++ct) acc[ct] = (floatx4)0.f;

        #pragma unroll
        for (int ks = 0; ks < 4; ++ks) {
            const float4 f0 = *(const float4*)(x + (size_t)row * DIN + ks * 32 + lg * 8);
            const float4 f1 = *(const float4*)(x + (size_t)row * DIN + ks * 32 + lg * 8 + 4);
            short8 af;
            af[0] = f2bf_bits(f0.x); af[1] = f2bf_bits(f0.y);
            af[2] = f2bf_bits(f0.z); af[3] = f2bf_bits(f0.w);
            af[4] = f2bf_bits(f1.x); af[5] = f2bf_bits(f1.y);
            af[6] = f2bf_bits(f1.z); af[7] = f2bf_bits(f1.w);
            #pragma unroll
            for (int ct = 0; ct < 8; ++ct)
                acc[ct] = __builtin_amdgcn_mfma_f32_16x16x32_bf16(
                    af, bf[ct][ks], acc[ct], 0, 0, 0);
        }

        #pragma unroll
        for (int reg = 0; reg < 4; ++reg) {
            const int r = tile * 16 + lg * 4 + reg;

            // h write (bf16)
            #pragma unroll
            for (int ct = 0; ct < 8; ++ct)
                if (r < n)
                    h[(size_t)r * HC + ct * 16 + l15] =
                        __float2bfloat16(acc[ct][reg] + bc[ct]);

            // fused logits: per-head dot over this row's 128 cols
            float pi[4], pj[4];
            #pragma unroll
            for (int hd = 0; hd < 4; ++hd) {
                float vi = 0.f, vj = 0.f;
                #pragma unroll
                for (int q = 0; q < 2; ++q) {
                    const int ct = hd * 2 + q;
                    const float hv = acc[ct][reg] + bc[ct];
                    vi = fmaf(hv, ai_l[ct], vi);
                    vj = fmaf(hv, aj_l[ct], vj);
                }
                #pragma unroll
                for (int m = 1; m <= 8; m <<= 1) {
                    vi += __shfl_xor(vi, m);
                    vj += __shfl_xor(vj, m);
                }
                pi[hd] = vi; pj[hd] = vj;
            }
            if (l15 < 8 && r < n) {
                const int hd = l15 & 3;
                float wi = pi[0];
                wi = (hd == 1) ? pi[1] : wi;
                wi = (hd == 2) ? pi[2] : wi;
                wi = (hd == 3) ? pi[3] : wi;
                float wj = pj[0];
                wj = (hd == 1) ? pj[1] : wj;
                wj = (hd == 2) ? pj[2] : wj;
                wj = (hd == 3) ? pj[3] : wj;
                if (l15 < 4) ali[(size_t)r * 4 + hd] = wi;
                else         alj[(size_t)r * 4 + hd] = wj;
            }
        }
    }
}

// ---------------------------------------------------------------------------
// ONE node per wave, edge list SPLIT between the two half-waves (even edges
// -> half 0, odd -> half 1). Each half covers all 128 cols (32 lanes x
// ushort4), unroll-4 per half = 8 edges in flight per wave. One
// shfl_xor(32) folds the halves; half 0 stores float4 with bias+ReLU.
// ---------------------------------------------------------------------------
__global__ __launch_bounds__(256) void aggregate_csr(
    const int* __restrict__ rowptr, const int* __restrict__ boff,
    const unsigned short* __restrict__ csr,
    const float* __restrict__ ali, const float* __restrict__ alj,
    const __hip_bfloat16* __restrict__ h, const float* __restrict__ bias,
    float* __restrict__ out, int n, int total)
{
    const int lane = threadIdx.x & 63;
    const int l32  = lane & 31;
    const int half = lane >> 5;
    const int hh   = l32 >> 3;                  // head of cols [l32*4, l32*4+4)
    const int gw = (blockIdx.x * 256 + threadIdx.x) >> 6;
    const int nw = (gridDim.x * 256) >> 6;
    const unsigned short* hu = (const unsigned short*)h;
    const float b0 = bias[l32 * 4 + 0], b1 = bias[l32 * 4 + 1];
    const float b2 = bias[l32 * 4 + 2], b3 = bias[l32 * 4 + 3];

    for (int i = gw; i < n; i += nw) {
        const int rs = rowptr[i] + boff[i >> 8];
        const int re = (i + 1 == n) ? total
                                    : rowptr[i + 1] + boff[(i + 1) >> 8];
        const float aii = ali[(size_t)i * 4 + hh];

        float a0 = 0.f, a1 = 0.f, a2 = 0.f, a3 = 0.f, s = 0.f;
        int t = rs + half;                      // this half's stream: stride 2
        for (; t + 6 < re; t += 8) {            // 4 edges per half per iter
            int jj[4]; float ll[4]; ushort4 uu[4];
            #pragma unroll
            for (int q = 0; q < 4; ++q) jj[q] = csr[t + q * 2];
            #pragma unroll
            for (int q = 0; q < 4; ++q) ll[q] = alj[(size_t)jj[q] * 4 + hh];
            #pragma unroll
            for (int q = 0; q < 4; ++q)
                uu[q] = *(const ushort4*)(hu + (size_t)jj[q] * HC + l32 * 4);
            #pragma unroll
            for (int q = 0; q < 4; ++q) {
                float l = aii + ll[q];
                l = l > 0.f ? l : 0.2f * l;
                const float ex = __expf(l);
                s += ex;
                a0 = fmaf(ex, bfbits2f(uu[q].x), a0);
                a1 = fmaf(ex, bfbits2f(uu[q].y), a1);
                a2 = fmaf(ex, bfbits2f(uu[q].z), a2);
                a3 = fmaf(ex, bfbits2f(uu[q].w), a3);
            }
        }
        for (; t < re; t += 2) {
            const int j = csr[t];
            float l = aii + alj[(size_t)j * 4 + hh];
            l = l > 0.f ? l : 0.2f * l;
            const float ex = __expf(l);
            s += ex;
            const ushort4 u = *(const ushort4*)(hu + (size_t)j * HC + l32 * 4);
            a0 = fmaf(ex, bfbits2f(u.x), a0);
            a1 = fmaf(ex, bfbits2f(u.y), a1);
            a2 = fmaf(ex, bfbits2f(u.z), a2);
            a3 = fmaf(ex, bfbits2f(u.w), a3);
        }

        // fold the two halves (lane l and l+32 hold the same columns)
        a0 += __shfl_xor(a0, 32);
        a1 += __shfl_xor(a1, 32);
        a2 += __shfl_xor(a2, 32);
        a3 += __shfl_xor(a3, 32);
        s  += __shfl_xor(s, 32);

        if (half == 0) {
            const float inv = 1.0f / s;
            float o0 = fmaf(a0, inv, b0);
            float o1 = fmaf(a1, inv, b1);
            float o2 = fmaf(a2, inv, b2);
            float o3 = fmaf(a3, inv, b3);
            float4 ov;
            ov.x = o0 > 0.f ? o0 : 0.f;
            ov.y = o1 > 0.f ? o1 : 0.f;
            ov.z = o2 > 0.f ? o2 : 0.f;
            ov.w = o3 > 0.f ? o3 : 0.f;
            *(float4*)(out + (size_t)i * HC + l32 * 4) = ov;
        }
    }
}

extern "C" void kernel_launch(void* const* d_in, const int* in_sizes, int n_in,
                              void* d_out, int out_size, void* d_ws, size_t ws_size,
                              hipStream_t stream)
{
    const float* x    = (const float*)d_in[0];
    const int*   ei   = (const int*)d_in[1];     // int32 (harness convention)
    const float* W    = (const float*)d_in[2];
    const float* b    = (const float*)d_in[3];
    const float* att  = (const float*)d_in[4];
    const float* bias = (const float*)d_in[5];

    const int n     = in_sizes[0] / DIN;   // 50000
    const int E     = in_sizes[1] / 2;     // 800000
    const int total = E + n;

    const int* src = ei;        // e_i (segment index)
    const int* dst = ei + E;    // e_j (gather index)

    const int nchunks = (total + CNK - 1) >> CHUNK_LOG;   // 26
    const int nb      = (n + 255) / 256;                  // scan blocks (196)

    // workspace layout (~20 MB), 256B-aligned slices
    char* ws = (char*)d_ws;
    size_t off = 0;
    auto take = [&](size_t bytes) {
        char* p = ws + off;
        off += (bytes + 255) & ~(size_t)255;
        return p;
    };
    __hip_bfloat16* h   = (__hip_bfloat16*)take((size_t)n * HC * 2);
    float* ali    = (float*)take((size_t)n * NH * 4);
    float* alj    = (float*)take((size_t)n * NH * 4);
    int*   rowptr = (int*)take((size_t)(n + 1) * 4);
    int*   bsum   = (int*)take((size_t)nb * 4);
    int*   boff   = (int*)take((size_t)nb * 4);
    unsigned short* cnt    = (unsigned short*)take((size_t)nchunks * n * 2);
    unsigned short* rank16 = (unsigned short*)take((size_t)total * 2);
    unsigned short* csr    = (unsigned short*)take((size_t)total * 2);

    float* out = (float*)d_out;

    hist<<<nchunks, 1024, 0, stream>>>(src, cnt, rank16, n, E, total);
    scan1<<<nb, 256, 0, stream>>>(cnt, rowptr, bsum, n, nchunks);
    scan2<<<1, 1024, 0, stream>>>(bsum, boff, nb);

    const int ntiles = (n + 15) / 16;
    gemm_scatter<<<GB + SB, 256, 0, stream>>>(
        x, W, b, att, h, ali, alj,
        src, dst, rank16, cnt, rowptr, boff, csr,
        n, ntiles, E, total);

    const int nodeBlocks = (n + 3) / 4;            // 4 waves/block, 1 node/wave
    aggregate_csr<<<nodeBlocks, 256, 0, stream>>>(rowptr, boff, csr, ali, alj,
                                                  h, bias, out, n, total);
}